// Round 14
// baseline (800.699 us; speedup 1.0000x reference)
//
#include <hip/hip_runtime.h>
#include <hip/hip_fp16.h>
#include <math.h>

#define N_NODES 100000
#define N_PAD   100352
#define N_EDGES 1600000
#define N_REL   3
#define BN_EPS  1e-5f

// Bucket sort parameters (CSR build)
#define BK    49         // coarse dst buckets = ceil(100000/2048)
#define BSH   11         // 2048 nodes per bucket
#define BMSK  2047
#define NBLK  250        // edge chunks per relation
#define EPB   6400       // edges per chunk (250*6400 == N_EDGES)

// Factorization: agg[n] = dinv[n] * sum_{e->n} hs[src_e], hs = h*dinv
// prescaled in the GEMM epilogue; self term recovered as hs[n]*rdinv[n].
// gather64 runs as 2 channel-halves (blockIdx.z): per-pass h working set
// 6.4 MB/relation -> per-XCD L2 (4 MiB) hit rate ~62% vs ~31% unsplit.

// ---------------------------------------------------------------- pass A: histogram
__global__ __launch_bounds__(256) void k_hist(const int* __restrict__ ei,
                                              int* __restrict__ offs,
                                              float* __restrict__ zeroRegion) {
    const int r = blockIdx.y;
    const int* dst = ei + (size_t)r * 2 * N_EDGES + N_EDGES;
    const int tid = threadIdx.x;
    if (blockIdx.x == 0 && r == 0) {
        for (int i = tid; i < N_REL * 192; i += 256) zeroRegion[i] = 0.0f;
    }
    __shared__ int hist[BK];
    if (tid < BK) hist[tid] = 0;
    __syncthreads();
    const int base = blockIdx.x * EPB;
    for (int i = tid; i < EPB; i += 256)
        atomicAdd(&hist[dst[base + i] >> BSH], 1);
    __syncthreads();
    if (tid < BK)
        offs[(size_t)r * BK * NBLK + tid * NBLK + blockIdx.x] = hist[tid];
}

// ---------------------------------------------------------------- pass B: scan (bucket-major)
__global__ __launch_bounds__(1024) void k_histscan(int* __restrict__ offs) {
    const int r = blockIdx.x;
    int* o = offs + (size_t)r * BK * NBLK;
    constexpr int LEN = BK * NBLK;           // 12250
    constexpr int PER = (LEN + 1023) / 1024; // 12
    __shared__ int sh[1024];
    const int t = threadIdx.x;
    const int base = t * PER;
    int pre[PER];
    int lsum = 0;
    #pragma unroll
    for (int i = 0; i < PER; ++i) {
        int idx = base + i;
        int v = (idx < LEN) ? o[idx] : 0;
        pre[i] = lsum;
        lsum += v;
    }
    sh[t] = lsum;
    __syncthreads();
    for (int s = 1; s < 1024; s <<= 1) {
        int add = (t >= s) ? sh[t - s] : 0;
        __syncthreads();
        sh[t] += add;
        __syncthreads();
    }
    const int myoff = sh[t] - lsum;
    #pragma unroll
    for (int i = 0; i < PER; ++i) {
        int idx = base + i;
        if (idx < LEN) o[idx] = myoff + pre[i];
    }
}

// ---------------------------------------------------------------- pass C: bin edges
__global__ __launch_bounds__(256) void k_bin(const int* __restrict__ ei,
                                             const int* __restrict__ offs,
                                             int* __restrict__ binned) {
    const int r = blockIdx.y;
    const int* src = ei + (size_t)r * 2 * N_EDGES;
    const int* dst = src + N_EDGES;
    int* bn = binned + (size_t)r * N_EDGES;
    const int tid = threadIdx.x;
    __shared__ int cur[BK];
    if (tid < BK)
        cur[tid] = offs[(size_t)r * BK * NBLK + tid * NBLK + blockIdx.x];
    __syncthreads();
    const int base = blockIdx.x * EPB;
    for (int i = tid; i < EPB; i += 256) {
        int s = src[base + i];
        int d = dst[base + i];
        int pos = atomicAdd(&cur[d >> BSH], 1);
        bn[pos] = s | ((d & BMSK) << 17);
    }
}

// ---------------------------------------------------------------- pass D: count+scan+scatter
__global__ __launch_bounds__(1024) void k_csr2(const int* __restrict__ binned,
                                               const int* __restrict__ offs,
                                               int* __restrict__ rowptr,
                                               float* __restrict__ dinvB,
                                               float* __restrict__ rdinvB,
                                               int* __restrict__ edsrc) {
    const int r = blockIdx.y;
    const int b = blockIdx.x;
    const int t = threadIdx.x;
    const int bbase = b << BSH;
    const int* o = offs + (size_t)r * BK * NBLK;
    const int start = o[b * NBLK];
    const int end = (b == BK - 1) ? N_EDGES : o[(b + 1) * NBLK];
    const int* bn = binned + (size_t)r * N_EDGES;
    int* ed = edsrc + (size_t)r * N_EDGES;
    int* rp = rowptr + (size_t)r * (N_PAD + 1);
    float* dinv  = dinvB  + (size_t)r * N_PAD;
    float* rdinv = rdinvB + (size_t)r * N_PAD;

    __shared__ int cnt[1 << BSH];
    __shared__ int ssum[1024];
    cnt[t] = 0;
    cnt[t + 1024] = 0;
    __syncthreads();
    for (int i = start + t; i < end; i += 1024)
        atomicAdd(&cnt[bn[i] >> 17], 1);
    __syncthreads();
    const int a0 = cnt[2 * t];
    const int a1 = cnt[2 * t + 1];
    const int lsum = a0 + a1;
    ssum[t] = lsum;
    __syncthreads();
    for (int s = 1; s < 1024; s <<= 1) {
        int add = (t >= s) ? ssum[t - s] : 0;
        __syncthreads();
        ssum[t] += add;
        __syncthreads();
    }
    const int ex = ssum[t] - lsum;
    const int p0 = start + ex;
    const int p1 = p0 + a0;
    const int n0g = bbase + 2 * t;
    if (n0g < N_NODES) {
        rp[n0g] = p0;
        float m = fmaxf((float)a0, 1.0f);
        float dv = rsqrtf(m);
        dinv[n0g] = dv;
        rdinv[n0g] = m * dv;
    }
    if (n0g + 1 < N_NODES) {
        rp[n0g + 1] = p1;
        float m = fmaxf((float)a1, 1.0f);
        float dv = rsqrtf(m);
        dinv[n0g + 1] = dv;
        rdinv[n0g + 1] = m * dv;
    }
    if (b == BK - 1 && t == 0) rp[N_NODES] = N_EDGES;
    cnt[2 * t] = p0;
    cnt[2 * t + 1] = p1;
    __syncthreads();
    for (int i = start + t; i < end; i += 1024) {
        int p = bn[i];
        int pos = atomicAdd(&cnt[p >> 17], 1);
        ed[pos] = p & 0x1FFFF;
    }
}

// ---------------------------------------------------------------- GEMM
__device__ __forceinline__ float ld_f(const float* p)  { return *p; }
__device__ __forceinline__ float ld_f(const __half* p) { return __half2float(*p); }

template<int K, int C, bool BN, typename TI>
__global__ __launch_bounds__(256) void k_gemm(const TI* __restrict__ Xb,
                                              size_t xStrideR,
                                              const float* __restrict__ Wb,
                                              const float* __restrict__ biasB,
                                              const float* __restrict__ bnsumB,
                                              const float* __restrict__ bnsqB,
                                              const float* __restrict__ bnScaleB,
                                              const float* __restrict__ bnBiasB,
                                              const float* __restrict__ dinvB,
                                              __half* __restrict__ Yb,
                                              int nodesPerBlock) {
    const int r = blockIdx.y;
    const TI* X = Xb + (size_t)r * xStrideR;
    const float* W = Wb + (size_t)r * K * C;
    const float* bias = biasB + (size_t)r * C;
    const float* dinv = dinvB + (size_t)r * N_PAD;
    __half* Y = Yb + (size_t)r * N_NODES * C;

    constexpr int CG = C / 4;
    constexpr int NPASS = 256 / CG;
    constexpr int XP = K + 1;
    __shared__ __align__(16) float Ws[K * C];
    __shared__ float Xs[NPASS * XP];
    __shared__ float seL[K], beL[K];
    const int tid = threadIdx.x;
    for (int i = tid; i < K * C; i += 256) Ws[i] = W[i];
    if (BN) {
        for (int i = tid; i < K; i += 256) {
            int gi = r * K + i;
            float m = bnsumB[gi] * (1.0f / N_NODES);
            float v = bnsqB[gi] * (1.0f / N_NODES) - m * m;
            float inv = rsqrtf(v + BN_EPS);
            float sc = inv * bnScaleB[gi];
            seL[i] = sc;
            beL[i] = bnBiasB[gi] - m * sc;
        }
    }
    const int cg = tid % CG;
    const int ln = tid / CG;
    const int c0 = cg * 4;
    const float4 bv = *(const float4*)&bias[c0];
    const int blockStart = blockIdx.x * nodesPerBlock;
    const int passes = nodesPerBlock / NPASS;
    for (int p = 0; p < passes; ++p) {
        const int node0 = blockStart + p * NPASS;
        __syncthreads();
        for (int i = tid; i < NPASS * K; i += 256) {
            int lnn = i / K, k = i % K;
            int n = node0 + lnn;
            float v = 0.0f;
            if (n < N_NODES) {
                v = ld_f(&X[(size_t)n * K + k]);
                if (BN) v = fmaxf(v * seL[k] + beL[k], 0.0f);
            }
            Xs[lnn * XP + k] = v;
        }
        __syncthreads();
        const int n = node0 + ln;
        float4 acc = bv;
        const float* xrow = &Xs[ln * XP];
        #pragma unroll 8
        for (int k = 0; k < K; ++k) {
            float f = xrow[k];
            float4 w = *(const float4*)&Ws[k * C + c0];
            acc.x += f * w.x;
            acc.y += f * w.y;
            acc.z += f * w.z;
            acc.w += f * w.w;
        }
        if (n < N_NODES) {
            const float dv = dinv[n];       // prescale: Y = hs = h * dinv
            ushort4 sv;
            sv.x = __half_as_ushort(__float2half_rn(acc.x * dv));
            sv.y = __half_as_ushort(__float2half_rn(acc.y * dv));
            sv.z = __half_as_ushort(__float2half_rn(acc.z * dv));
            sv.w = __half_as_ushort(__float2half_rn(acc.w * dv));
            *(ushort4*)&Y[(size_t)n * C + c0] = sv;
        }
    }
}

// ---------------------------------------------------------------- gather-agg
// C = channels processed per block, HS = h/X row stride (elements).
// blockIdx.z = channel-pass (HS/C passes); per-pass h working set = HS/C
// smaller -> higher per-XCD L2 hit rate on the random row gathers.
// x[n][ch] = g * dinv[n] * sum_e hs[src_e][ch] + (1-g) * rdinv[n] * hs[n][ch]
template<int C, int HS, int NPB, typename TO>
__global__ __launch_bounds__(256) void k_gather(const __half* __restrict__ hB,
                                                const int* __restrict__ rowptrB,
                                                const int* __restrict__ edsB,
                                                const float* __restrict__ dinvB,
                                                const float* __restrict__ rdinvB,
                                                const float* __restrict__ gammaP,
                                                TO* __restrict__ XB,
                                                float* __restrict__ bnsumB,
                                                float* __restrict__ bnsqB) {
    const int r = blockIdx.y;
    const int choff = blockIdx.z * C;
    const __half* h = hB + (size_t)r * N_NODES * HS;
    const int* rowptr = rowptrB + (size_t)r * (N_PAD + 1);
    const int* edg = edsB + (size_t)r * N_EDGES;
    const float* dinv  = dinvB  + (size_t)r * N_PAD;
    const float* rdinv = rdinvB + (size_t)r * N_PAD;
    TO* X = XB + (size_t)r * N_NODES * HS;
    float* bnsum = bnsumB + (size_t)r * HS + choff;
    float* bnsq  = bnsqB  + (size_t)r * HS + choff;

    constexpr int WPB = 256 / C;
    constexpr int RPS = NPB / WPB;
    constexpr int CH  = 4096;           // LDS edge chunk (16 KB, 4B entries)
    __shared__ int eds[CH];
    __shared__ int rp[NPB + 1];
    __shared__ float red[256];
    const int tid = threadIdx.x;
    const int c = tid % C;
    const int slot = tid / C;
    const float g = gammaP[r];
    const float gi = 1.0f - g;
    const int n0 = blockIdx.x * NPB;
    const __half* hc = h + choff + c;
    if (tid <= NPB) {
        int n = n0 + tid;
        rp[tid] = rowptr[(n <= N_NODES) ? n : N_NODES];
    }
    __syncthreads();
    const int bs = rp[0];
    const int bEnd = rp[NPB];
    int rs[RPS], re[RPS];
    float acc[RPS];
    #pragma unroll
    for (int i = 0; i < RPS; ++i) {
        int ri = slot + i * WPB;
        rs[i] = rp[ri];
        re[i] = rp[ri + 1];
        acc[i] = 0.0f;
    }
    for (int ck = bs; ck < bEnd; ck += CH) {
        const int c1 = min(ck + CH, bEnd);
        const int cnt = c1 - ck;
        __syncthreads();
        for (int j = tid; j < cnt; j += 256) eds[j] = edg[ck + j];
        __syncthreads();
        #pragma unroll
        for (int i = 0; i < RPS; ++i) {
            const int lo = max(rs[i], ck);
            const int hi = min(re[i], c1);
            if (lo >= hi) continue;
            float a = acc[i];
            int e = lo;
            const int efull = lo + ((hi - lo) & ~7);
            for (; e < efull; e += 8) {           // clamp-free main body
                int ed[8];
                #pragma unroll
                for (int j = 0; j < 8; ++j) ed[j] = eds[e - ck + j];
                float v[8];
                #pragma unroll
                for (int j = 0; j < 8; ++j)
                    v[j] = __half2float(hc[(unsigned)ed[j] * HS]);
                #pragma unroll
                for (int j = 0; j < 8; ++j) a += v[j];
            }
            if (e < hi) {                         // single clamped tail batch
                int ed[8];
                #pragma unroll
                for (int j = 0; j < 8; ++j) {
                    int t = e + j;
                    ed[j] = eds[((t < hi) ? t : lo) - ck];
                }
                float v[8];
                #pragma unroll
                for (int j = 0; j < 8; ++j)
                    v[j] = __half2float(hc[(unsigned)ed[j] * HS]);
                #pragma unroll
                for (int j = 0; j < 8; ++j)
                    a += (e + j < hi) ? v[j] : 0.0f;
            }
            acc[i] = a;
        }
    }
    float s = 0.0f, sq = 0.0f;
    #pragma unroll
    for (int i = 0; i < RPS; ++i) {
        int n = n0 + slot + i * WPB;
        if (n < N_NODES) {
            float x = g * dinv[n] * acc[i]
                    + gi * rdinv[n] * __half2float(hc[(unsigned)n * HS]);
            if constexpr (sizeof(TO) == 2)
                X[(size_t)n * HS + choff + c] = __float2half_rn(x);
            else
                X[(size_t)n * HS + choff + c] = x;
            s += x;
            sq += x * x;
        }
    }
    __syncthreads();
    red[tid] = s;
    __syncthreads();
    if (slot == 0) {
        float t = 0.0f;
        #pragma unroll
        for (int i = 0; i < WPB; ++i) t += red[c + i * C];
        atomicAdd(&bnsum[c], t);
    }
    __syncthreads();
    red[tid] = sq;
    __syncthreads();
    if (slot == 0) {
        float t = 0.0f;
        #pragma unroll
        for (int i = 0; i < WPB; ++i) t += red[c + i * C];
        atomicAdd(&bnsq[c], t);
    }
}

// ---------------------------------------------------------------- output
__global__ __launch_bounds__(256) void k_out(const float* __restrict__ x2B,
                                             const int* __restrict__ batch,
                                             const float* __restrict__ bnsumB,
                                             const float* __restrict__ bnsqB,
                                             const float* __restrict__ scaleB,
                                             const float* __restrict__ biasB,
                                             float* __restrict__ out) {
    const int r = blockIdx.y;
    const float* x2 = x2B + (size_t)r * N_NODES * 32;
    __shared__ float seL[32], beL[32];
    if (threadIdx.x < 32) {
        int gi = r * 32 + threadIdx.x;
        float m = bnsumB[gi] * (1.0f / N_NODES);
        float v = bnsqB[gi] * (1.0f / N_NODES) - m * m;
        float inv = rsqrtf(v + BN_EPS);
        float sc = inv * scaleB[gi];
        seL[threadIdx.x] = sc;
        beL[threadIdx.x] = biasB[gi] - m * sc;
    }
    __syncthreads();
    int gid = blockIdx.x * 256 + threadIdx.x;
    int b = gid >> 5;
    int c = gid & 31;
    if (b < 50000) {
        int node = batch[b];
        float y = fmaxf(x2[(size_t)node * 32 + c] * seL[c] + beL[c], 0.0f);
        float m = y;
        #pragma unroll
        for (int off = 16; off; off >>= 1) m = fmaxf(m, __shfl_xor(m, off, 32));
        float ex = __expf(y - m);
        float ssum = ex;
        #pragma unroll
        for (int off = 16; off; off >>= 1) ssum += __shfl_xor(ssum, off, 32);
        out[(size_t)b * (N_REL * 32) + r * 32 + c] = (y - m) - __logf(ssum);
    }
}

// ---------------------------------------------------------------- launcher
extern "C" void kernel_launch(void* const* d_in, const int* in_sizes, int n_in,
                              void* d_out, int out_size, void* d_ws, size_t ws_size,
                              hipStream_t stream) {
    const float* features    = (const float*)d_in[0];
    const int*   edge_index  = (const int*)d_in[1];
    const int*   batch_nodes = (const int*)d_in[2];
    const float* W1          = (const float*)d_in[3];
    const float* b1          = (const float*)d_in[4];
    const float* W2          = (const float*)d_in[5];
    const float* b2          = (const float*)d_in[6];
    const float* gamma1      = (const float*)d_in[7];
    const float* gamma2      = (const float*)d_in[8];
    const float* bn1_scale   = (const float*)d_in[9];
    const float* bn1_bias    = (const float*)d_in[10];
    const float* bn2_scale   = (const float*)d_in[11];
    const float* bn2_bias    = (const float*)d_in[12];
    float* out = (float*)d_out;

    // ---- workspace layout (byte offsets, 16B aligned), relation-batched ----
    char* wsB = (char*)d_ws;
    size_t off = 0;
    auto alloc = [&](size_t bytes) {
        void* p = wsB + off;
        off = (off + bytes + 15) & ~(size_t)15;
        return p;
    };
    // BN accumulators first: contiguous N_REL*192 floats, zeroed by k_hist
    float* bnsum1 = (float*)alloc(N_REL * 64 * 4);
    float* bnsq1  = (float*)alloc(N_REL * 64 * 4);
    float* bnsum2 = (float*)alloc(N_REL * 32 * 4);
    float* bnsq2  = (float*)alloc(N_REL * 32 * 4);
    float* zeroRegion = bnsum1;
    // scratch
    float* dinv      = (float*)alloc((size_t)N_REL * N_PAD * 4);
    float* rdinv     = (float*)alloc((size_t)N_REL * N_PAD * 4);
    int*   rowptr    = (int*)alloc((size_t)N_REL * (N_PAD + 1) * 4);
    int*   offs      = (int*)alloc((size_t)N_REL * BK * NBLK * 4);   // 147 KB
    int*    edsrc = (int*)alloc((size_t)N_REL * N_EDGES * 4);        // 19.2 MB
    __half* h1   = (__half*)alloc((size_t)N_REL * N_NODES * 64 * 2); // 38.4 MB (hs)
    __half* x1   = (__half*)alloc((size_t)N_REL * N_NODES * 64 * 2); // 38.4 MB
    __half* h2   = (__half*)alloc((size_t)N_REL * N_NODES * 32 * 2); // 19.2 MB (hs)
    float*  x2   = (float*)h1;   // alias: h1 dead after gather64
    int*  binned = (int*)x1;     // alias: binned dead before gather64 writes x1

    // ---- CSR build (also zeroes BN accumulators in k_hist) ----
    k_hist<<<dim3(NBLK, N_REL), 256, 0, stream>>>(edge_index, offs, zeroRegion);
    k_histscan<<<N_REL, 1024, 0, stream>>>(offs);
    k_bin<<<dim3(NBLK, N_REL), 256, 0, stream>>>(edge_index, offs, binned);
    k_csr2<<<dim3(BK, N_REL), 1024, 0, stream>>>(binned, offs, rowptr,
                                                 dinv, rdinv, edsrc);

    // ---- conv1 ----
    k_gemm<128, 64, false, float><<<dim3((N_NODES + 63) / 64, N_REL), 256, 0, stream>>>(
        features, 0, W1, b1, nullptr, nullptr, nullptr, nullptr, dinv, h1, 64);
    // gather64: 2 channel-passes (z), each pass reads one 64B line per edge
    k_gather<32, 64, 64, __half><<<dim3((N_NODES + 63) / 64, N_REL, 2), 256, 0, stream>>>(
        h1, rowptr, edsrc, dinv, rdinv, gamma1, x1, bnsum1, bnsq1);

    // ---- conv2 (BN1 finalize + relu fused into GEMM load) ----
    k_gemm<64, 32, true, __half><<<dim3((N_NODES + 127) / 128, N_REL), 256, 0, stream>>>(
        x1, (size_t)N_NODES * 64, W2, b2, bnsum1, bnsq1, bn1_scale, bn1_bias,
        dinv, h2, 128);
    k_gather<32, 32, 64, float><<<dim3((N_NODES + 63) / 64, N_REL, 1), 256, 0, stream>>>(
        h2, rowptr, edsrc, dinv, rdinv, gamma2, x2, bnsum2, bnsq2);

    // ---- output (BN2 finalize inlined) ----
    k_out<<<dim3((50000 * 32 + 255) / 256, N_REL), 256, 0, stream>>>(
        x2, batch_nodes, bnsum2, bnsq2, bn2_scale, bn2_bias, out);
}

// Round 15
// 782.713 us; speedup vs baseline: 1.0230x; 1.0230x over previous
//
#include <hip/hip_runtime.h>
#include <hip/hip_fp16.h>
#include <math.h>

#define N_NODES 100000
#define N_PAD   100352
#define N_EDGES 1600000
#define N_REL   3
#define BN_EPS  1e-5f

// Bucket sort parameters (CSR build)
#define BK    49         // coarse dst buckets = ceil(100000/2048)
#define BSH   11         // 2048 nodes per bucket
#define BMSK  2047
#define NBLK  250        // edge chunks per relation
#define EPB   6400       // edges per chunk (250*6400 == N_EDGES)

// Factorization: agg[n] = dinv[n] * sum_{e->n} hs[src_e], hs = h*dinv
// prescaled in the GEMM epilogue; self term recovered as hs[n]*rdinv[n].
// NOTE (r14 post-mortem): gather is L2 line-transaction bound (~2 lines/edge
// at fp16 128B rows); channel-splitting doubles edge processing at equal
// transactions -> reverted to single-pass C=64.

// ---------------------------------------------------------------- pass A: histogram
// 4-way replicated LDS histogram (atomic serialization /4), int4 dst reads.
__global__ __launch_bounds__(256) void k_hist(const int* __restrict__ ei,
                                              int* __restrict__ offs,
                                              float* __restrict__ zeroRegion) {
    const int r = blockIdx.y;
    const int* dst = ei + (size_t)r * 2 * N_EDGES + N_EDGES;
    const int tid = threadIdx.x;
    if (blockIdx.x == 0 && r == 0) {
        for (int i = tid; i < N_REL * 192; i += 256) zeroRegion[i] = 0.0f;
    }
    __shared__ int hist[4][BK];
    for (int i = tid; i < 4 * BK; i += 256) (&hist[0][0])[i] = 0;
    __syncthreads();
    const int4* d4 = (const int4*)(dst + blockIdx.x * EPB);
    const int cpy = tid & 3;
    for (int i = tid; i < EPB / 4; i += 256) {
        int4 v = d4[i];
        atomicAdd(&hist[cpy][v.x >> BSH], 1);
        atomicAdd(&hist[cpy][v.y >> BSH], 1);
        atomicAdd(&hist[cpy][v.z >> BSH], 1);
        atomicAdd(&hist[cpy][v.w >> BSH], 1);
    }
    __syncthreads();
    if (tid < BK)
        offs[(size_t)r * BK * NBLK + tid * NBLK + blockIdx.x] =
            hist[0][tid] + hist[1][tid] + hist[2][tid] + hist[3][tid];
}

// ---------------------------------------------------------------- pass B: scan (bucket-major)
__global__ __launch_bounds__(1024) void k_histscan(int* __restrict__ offs) {
    const int r = blockIdx.x;
    int* o = offs + (size_t)r * BK * NBLK;
    constexpr int LEN = BK * NBLK;           // 12250
    constexpr int PER = (LEN + 1023) / 1024; // 12
    __shared__ int sh[1024];
    const int t = threadIdx.x;
    const int base = t * PER;
    int pre[PER];
    int lsum = 0;
    #pragma unroll
    for (int i = 0; i < PER; ++i) {
        int idx = base + i;
        int v = (idx < LEN) ? o[idx] : 0;
        pre[i] = lsum;
        lsum += v;
    }
    sh[t] = lsum;
    __syncthreads();
    for (int s = 1; s < 1024; s <<= 1) {
        int add = (t >= s) ? sh[t - s] : 0;
        __syncthreads();
        sh[t] += add;
        __syncthreads();
    }
    const int myoff = sh[t] - lsum;
    #pragma unroll
    for (int i = 0; i < PER; ++i) {
        int idx = base + i;
        if (idx < LEN) o[idx] = myoff + pre[i];
    }
}

// ---------------------------------------------------------------- pass C: bin edges
// int4-vectorized src/dst reads; packed entry src | dstLocal<<17.
__global__ __launch_bounds__(256) void k_bin(const int* __restrict__ ei,
                                             const int* __restrict__ offs,
                                             int* __restrict__ binned) {
    const int r = blockIdx.y;
    const int* src = ei + (size_t)r * 2 * N_EDGES;
    const int* dst = src + N_EDGES;
    int* bn = binned + (size_t)r * N_EDGES;
    const int tid = threadIdx.x;
    __shared__ int cur[BK];
    if (tid < BK)
        cur[tid] = offs[(size_t)r * BK * NBLK + tid * NBLK + blockIdx.x];
    __syncthreads();
    const int4* s4p = (const int4*)(src + blockIdx.x * EPB);
    const int4* d4p = (const int4*)(dst + blockIdx.x * EPB);
    for (int i = tid; i < EPB / 4; i += 256) {
        int4 s4 = s4p[i];
        int4 dd = d4p[i];
        int p0 = atomicAdd(&cur[dd.x >> BSH], 1);
        bn[p0] = s4.x | ((dd.x & BMSK) << 17);
        int p1 = atomicAdd(&cur[dd.y >> BSH], 1);
        bn[p1] = s4.y | ((dd.y & BMSK) << 17);
        int p2 = atomicAdd(&cur[dd.z >> BSH], 1);
        bn[p2] = s4.z | ((dd.z & BMSK) << 17);
        int p3 = atomicAdd(&cur[dd.w >> BSH], 1);
        bn[p3] = s4.w | ((dd.w & BMSK) << 17);
    }
}

// ---------------------------------------------------------------- pass D: count+scan+scatter
__global__ __launch_bounds__(1024) void k_csr2(const int* __restrict__ binned,
                                               const int* __restrict__ offs,
                                               int* __restrict__ rowptr,
                                               float* __restrict__ dinvB,
                                               float* __restrict__ rdinvB,
                                               int* __restrict__ edsrc) {
    const int r = blockIdx.y;
    const int b = blockIdx.x;
    const int t = threadIdx.x;
    const int bbase = b << BSH;
    const int* o = offs + (size_t)r * BK * NBLK;
    const int start = o[b * NBLK];
    const int end = (b == BK - 1) ? N_EDGES : o[(b + 1) * NBLK];
    const int* bn = binned + (size_t)r * N_EDGES;
    int* ed = edsrc + (size_t)r * N_EDGES;
    int* rp = rowptr + (size_t)r * (N_PAD + 1);
    float* dinv  = dinvB  + (size_t)r * N_PAD;
    float* rdinv = rdinvB + (size_t)r * N_PAD;

    __shared__ int cnt[1 << BSH];
    __shared__ int ssum[1024];
    cnt[t] = 0;
    cnt[t + 1024] = 0;
    __syncthreads();
    for (int i = start + t; i < end; i += 1024)
        atomicAdd(&cnt[bn[i] >> 17], 1);
    __syncthreads();
    const int a0 = cnt[2 * t];
    const int a1 = cnt[2 * t + 1];
    const int lsum = a0 + a1;
    ssum[t] = lsum;
    __syncthreads();
    for (int s = 1; s < 1024; s <<= 1) {
        int add = (t >= s) ? ssum[t - s] : 0;
        __syncthreads();
        ssum[t] += add;
        __syncthreads();
    }
    const int ex = ssum[t] - lsum;
    const int p0 = start + ex;
    const int p1 = p0 + a0;
    const int n0g = bbase + 2 * t;
    if (n0g < N_NODES) {
        rp[n0g] = p0;
        float m = fmaxf((float)a0, 1.0f);
        float dv = rsqrtf(m);
        dinv[n0g] = dv;
        rdinv[n0g] = m * dv;
    }
    if (n0g + 1 < N_NODES) {
        rp[n0g + 1] = p1;
        float m = fmaxf((float)a1, 1.0f);
        float dv = rsqrtf(m);
        dinv[n0g + 1] = dv;
        rdinv[n0g + 1] = m * dv;
    }
    if (b == BK - 1 && t == 0) rp[N_NODES] = N_EDGES;
    cnt[2 * t] = p0;
    cnt[2 * t + 1] = p1;
    __syncthreads();
    for (int i = start + t; i < end; i += 1024) {
        int p = bn[i];
        int pos = atomicAdd(&cnt[p >> 17], 1);
        ed[pos] = p & 0x1FFFF;
    }
}

// ---------------------------------------------------------------- GEMM
__device__ __forceinline__ float ld_f(const float* p)  { return *p; }
__device__ __forceinline__ float ld_f(const __half* p) { return __half2float(*p); }

template<int K, int C, bool BN, typename TI>
__global__ __launch_bounds__(256) void k_gemm(const TI* __restrict__ Xb,
                                              size_t xStrideR,
                                              const float* __restrict__ Wb,
                                              const float* __restrict__ biasB,
                                              const float* __restrict__ bnsumB,
                                              const float* __restrict__ bnsqB,
                                              const float* __restrict__ bnScaleB,
                                              const float* __restrict__ bnBiasB,
                                              const float* __restrict__ dinvB,
                                              __half* __restrict__ Yb,
                                              int nodesPerBlock) {
    const int r = blockIdx.y;
    const TI* X = Xb + (size_t)r * xStrideR;
    const float* W = Wb + (size_t)r * K * C;
    const float* bias = biasB + (size_t)r * C;
    const float* dinv = dinvB + (size_t)r * N_PAD;
    __half* Y = Yb + (size_t)r * N_NODES * C;

    constexpr int CG = C / 4;
    constexpr int NPASS = 256 / CG;
    constexpr int XP = K + 1;
    __shared__ __align__(16) float Ws[K * C];
    __shared__ float Xs[NPASS * XP];
    __shared__ float seL[K], beL[K];
    const int tid = threadIdx.x;
    for (int i = tid; i < K * C; i += 256) Ws[i] = W[i];
    if (BN) {
        for (int i = tid; i < K; i += 256) {
            int gi = r * K + i;
            float m = bnsumB[gi] * (1.0f / N_NODES);
            float v = bnsqB[gi] * (1.0f / N_NODES) - m * m;
            float inv = rsqrtf(v + BN_EPS);
            float sc = inv * bnScaleB[gi];
            seL[i] = sc;
            beL[i] = bnBiasB[gi] - m * sc;
        }
    }
    const int cg = tid % CG;
    const int ln = tid / CG;
    const int c0 = cg * 4;
    const float4 bv = *(const float4*)&bias[c0];
    const int blockStart = blockIdx.x * nodesPerBlock;
    const int passes = nodesPerBlock / NPASS;
    for (int p = 0; p < passes; ++p) {
        const int node0 = blockStart + p * NPASS;
        __syncthreads();
        for (int i = tid; i < NPASS * K; i += 256) {
            int lnn = i / K, k = i % K;
            int n = node0 + lnn;
            float v = 0.0f;
            if (n < N_NODES) {
                v = ld_f(&X[(size_t)n * K + k]);
                if (BN) v = fmaxf(v * seL[k] + beL[k], 0.0f);
            }
            Xs[lnn * XP + k] = v;
        }
        __syncthreads();
        const int n = node0 + ln;
        float4 acc = bv;
        const float* xrow = &Xs[ln * XP];
        #pragma unroll 8
        for (int k = 0; k < K; ++k) {
            float f = xrow[k];
            float4 w = *(const float4*)&Ws[k * C + c0];
            acc.x += f * w.x;
            acc.y += f * w.y;
            acc.z += f * w.z;
            acc.w += f * w.w;
        }
        if (n < N_NODES) {
            const float dv = dinv[n];       // prescale: Y = hs = h * dinv
            ushort4 sv;
            sv.x = __half_as_ushort(__float2half_rn(acc.x * dv));
            sv.y = __half_as_ushort(__float2half_rn(acc.y * dv));
            sv.z = __half_as_ushort(__float2half_rn(acc.z * dv));
            sv.w = __half_as_ushort(__float2half_rn(acc.w * dv));
            *(ushort4*)&Y[(size_t)n * C + c0] = sv;
        }
    }
}

// ---------------------------------------------------------------- gather-agg
// x[n] = g * dinv[n] * sum_e hs[src_e]  +  (1-g) * rdinv[n] * hs[n]
template<int C, int NPB, typename TO>
__global__ __launch_bounds__(256) void k_gather(const __half* __restrict__ hB,
                                                const int* __restrict__ rowptrB,
                                                const int* __restrict__ edsB,
                                                const float* __restrict__ dinvB,
                                                const float* __restrict__ rdinvB,
                                                const float* __restrict__ gammaP,
                                                TO* __restrict__ XB,
                                                float* __restrict__ bnsumB,
                                                float* __restrict__ bnsqB) {
    const int r = blockIdx.y;
    const __half* h = hB + (size_t)r * N_NODES * C;
    const int* rowptr = rowptrB + (size_t)r * (N_PAD + 1);
    const int* edg = edsB + (size_t)r * N_EDGES;
    const float* dinv  = dinvB  + (size_t)r * N_PAD;
    const float* rdinv = rdinvB + (size_t)r * N_PAD;
    TO* X = XB + (size_t)r * N_NODES * C;
    float* bnsum = bnsumB + (size_t)r * C;
    float* bnsq  = bnsqB  + (size_t)r * C;

    constexpr int WPB = 256 / C;
    constexpr int RPS = NPB / WPB;
    constexpr int CH  = 4096;           // LDS edge chunk (16 KB, 4B entries)
    __shared__ int eds[CH];
    __shared__ int rp[NPB + 1];
    __shared__ float red[256];
    const int tid = threadIdx.x;
    const int c = tid % C;
    const int slot = tid / C;
    const float g = gammaP[r];
    const float gi = 1.0f - g;
    const int n0 = blockIdx.x * NPB;
    const __half* hc = h + c;
    if (tid <= NPB) {
        int n = n0 + tid;
        rp[tid] = rowptr[(n <= N_NODES) ? n : N_NODES];
    }
    __syncthreads();
    const int bs = rp[0];
    const int bEnd = rp[NPB];
    int rs[RPS], re[RPS];
    float acc[RPS];
    #pragma unroll
    for (int i = 0; i < RPS; ++i) {
        int ri = slot + i * WPB;
        rs[i] = rp[ri];
        re[i] = rp[ri + 1];
        acc[i] = 0.0f;
    }
    for (int ck = bs; ck < bEnd; ck += CH) {
        const int c1 = min(ck + CH, bEnd);
        const int cnt = c1 - ck;
        __syncthreads();
        for (int j = tid; j < cnt; j += 256) eds[j] = edg[ck + j];
        __syncthreads();
        #pragma unroll
        for (int i = 0; i < RPS; ++i) {
            const int lo = max(rs[i], ck);
            const int hi = min(re[i], c1);
            if (lo >= hi) continue;
            float a = acc[i];
            int e = lo;
            const int efull = lo + ((hi - lo) & ~7);
            for (; e < efull; e += 8) {           // clamp-free main body
                int ed[8];
                #pragma unroll
                for (int j = 0; j < 8; ++j) ed[j] = eds[e - ck + j];
                float v[8];
                #pragma unroll
                for (int j = 0; j < 8; ++j)
                    v[j] = __half2float(hc[(unsigned)ed[j] * C]);
                #pragma unroll
                for (int j = 0; j < 8; ++j) a += v[j];
            }
            if (e < hi) {                         // single clamped tail batch
                int ed[8];
                #pragma unroll
                for (int j = 0; j < 8; ++j) {
                    int t = e + j;
                    ed[j] = eds[((t < hi) ? t : lo) - ck];
                }
                float v[8];
                #pragma unroll
                for (int j = 0; j < 8; ++j)
                    v[j] = __half2float(hc[(unsigned)ed[j] * C]);
                #pragma unroll
                for (int j = 0; j < 8; ++j)
                    a += (e + j < hi) ? v[j] : 0.0f;
            }
            acc[i] = a;
        }
    }
    float s = 0.0f, sq = 0.0f;
    #pragma unroll
    for (int i = 0; i < RPS; ++i) {
        int n = n0 + slot + i * WPB;
        if (n < N_NODES) {
            float x = g * dinv[n] * acc[i]
                    + gi * rdinv[n] * __half2float(hc[(unsigned)n * C]);
            if constexpr (sizeof(TO) == 2)
                X[(size_t)n * C + c] = __float2half_rn(x);
            else
                X[(size_t)n * C + c] = x;
            s += x;
            sq += x * x;
        }
    }
    __syncthreads();
    red[tid] = s;
    __syncthreads();
    if (slot == 0) {
        float t = 0.0f;
        #pragma unroll
        for (int i = 0; i < WPB; ++i) t += red[c + i * C];
        atomicAdd(&bnsum[c], t);
    }
    __syncthreads();
    red[tid] = sq;
    __syncthreads();
    if (slot == 0) {
        float t = 0.0f;
        #pragma unroll
        for (int i = 0; i < WPB; ++i) t += red[c + i * C];
        atomicAdd(&bnsq[c], t);
    }
}

// ---------------------------------------------------------------- output
__global__ __launch_bounds__(256) void k_out(const float* __restrict__ x2B,
                                             const int* __restrict__ batch,
                                             const float* __restrict__ bnsumB,
                                             const float* __restrict__ bnsqB,
                                             const float* __restrict__ scaleB,
                                             const float* __restrict__ biasB,
                                             float* __restrict__ out) {
    const int r = blockIdx.y;
    const float* x2 = x2B + (size_t)r * N_NODES * 32;
    __shared__ float seL[32], beL[32];
    if (threadIdx.x < 32) {
        int gi = r * 32 + threadIdx.x;
        float m = bnsumB[gi] * (1.0f / N_NODES);
        float v = bnsqB[gi] * (1.0f / N_NODES) - m * m;
        float inv = rsqrtf(v + BN_EPS);
        float sc = inv * scaleB[gi];
        seL[threadIdx.x] = sc;
        beL[threadIdx.x] = biasB[gi] - m * sc;
    }
    __syncthreads();
    int gid = blockIdx.x * 256 + threadIdx.x;
    int b = gid >> 5;
    int c = gid & 31;
    if (b < 50000) {
        int node = batch[b];
        float y = fmaxf(x2[(size_t)node * 32 + c] * seL[c] + beL[c], 0.0f);
        float m = y;
        #pragma unroll
        for (int off = 16; off; off >>= 1) m = fmaxf(m, __shfl_xor(m, off, 32));
        float ex = __expf(y - m);
        float ssum = ex;
        #pragma unroll
        for (int off = 16; off; off >>= 1) ssum += __shfl_xor(ssum, off, 32);
        out[(size_t)b * (N_REL * 32) + r * 32 + c] = (y - m) - __logf(ssum);
    }
}

// ---------------------------------------------------------------- launcher
extern "C" void kernel_launch(void* const* d_in, const int* in_sizes, int n_in,
                              void* d_out, int out_size, void* d_ws, size_t ws_size,
                              hipStream_t stream) {
    const float* features    = (const float*)d_in[0];
    const int*   edge_index  = (const int*)d_in[1];
    const int*   batch_nodes = (const int*)d_in[2];
    const float* W1          = (const float*)d_in[3];
    const float* b1          = (const float*)d_in[4];
    const float* W2          = (const float*)d_in[5];
    const float* b2          = (const float*)d_in[6];
    const float* gamma1      = (const float*)d_in[7];
    const float* gamma2      = (const float*)d_in[8];
    const float* bn1_scale   = (const float*)d_in[9];
    const float* bn1_bias    = (const float*)d_in[10];
    const float* bn2_scale   = (const float*)d_in[11];
    const float* bn2_bias    = (const float*)d_in[12];
    float* out = (float*)d_out;

    // ---- workspace layout (byte offsets, 16B aligned), relation-batched ----
    char* wsB = (char*)d_ws;
    size_t off = 0;
    auto alloc = [&](size_t bytes) {
        void* p = wsB + off;
        off = (off + bytes + 15) & ~(size_t)15;
        return p;
    };
    // BN accumulators first: contiguous N_REL*192 floats, zeroed by k_hist
    float* bnsum1 = (float*)alloc(N_REL * 64 * 4);
    float* bnsq1  = (float*)alloc(N_REL * 64 * 4);
    float* bnsum2 = (float*)alloc(N_REL * 32 * 4);
    float* bnsq2  = (float*)alloc(N_REL * 32 * 4);
    float* zeroRegion = bnsum1;
    // scratch
    float* dinv      = (float*)alloc((size_t)N_REL * N_PAD * 4);
    float* rdinv     = (float*)alloc((size_t)N_REL * N_PAD * 4);
    int*   rowptr    = (int*)alloc((size_t)N_REL * (N_PAD + 1) * 4);
    int*   offs      = (int*)alloc((size_t)N_REL * BK * NBLK * 4);   // 147 KB
    int*    edsrc = (int*)alloc((size_t)N_REL * N_EDGES * 4);        // 19.2 MB
    __half* h1   = (__half*)alloc((size_t)N_REL * N_NODES * 64 * 2); // 38.4 MB (hs)
    __half* x1   = (__half*)alloc((size_t)N_REL * N_NODES * 64 * 2); // 38.4 MB
    __half* h2   = (__half*)alloc((size_t)N_REL * N_NODES * 32 * 2); // 19.2 MB (hs)
    float*  x2   = (float*)h1;   // alias: h1 dead after gather64
    int*  binned = (int*)x1;     // alias: binned dead before gather64 writes x1

    // ---- CSR build (also zeroes BN accumulators in k_hist) ----
    k_hist<<<dim3(NBLK, N_REL), 256, 0, stream>>>(edge_index, offs, zeroRegion);
    k_histscan<<<N_REL, 1024, 0, stream>>>(offs);
    k_bin<<<dim3(NBLK, N_REL), 256, 0, stream>>>(edge_index, offs, binned);
    k_csr2<<<dim3(BK, N_REL), 1024, 0, stream>>>(binned, offs, rowptr,
                                                 dinv, rdinv, edsrc);

    // ---- conv1 ----
    k_gemm<128, 64, false, float><<<dim3((N_NODES + 63) / 64, N_REL), 256, 0, stream>>>(
        features, 0, W1, b1, nullptr, nullptr, nullptr, nullptr, dinv, h1, 64);
    k_gather<64, 32, __half><<<dim3((N_NODES + 31) / 32, N_REL), 256, 0, stream>>>(
        h1, rowptr, edsrc, dinv, rdinv, gamma1, x1, bnsum1, bnsq1);

    // ---- conv2 (BN1 finalize + relu fused into GEMM load) ----
    k_gemm<64, 32, true, __half><<<dim3((N_NODES + 127) / 128, N_REL), 256, 0, stream>>>(
        x1, (size_t)N_NODES * 64, W2, b2, bnsum1, bnsq1, bn1_scale, bn1_bias,
        dinv, h2, 128);
    k_gather<32, 64, float><<<dim3((N_NODES + 63) / 64, N_REL), 256, 0, stream>>>(
        h2, rowptr, edsrc, dinv, rdinv, gamma2, x2, bnsum2, bnsq2);

    // ---- output (BN2 finalize inlined) ----
    k_out<<<dim3((50000 * 32 + 255) / 256, N_REL), 256, 0, stream>>>(
        x2, batch_nodes, bnsum2, bnsq2, bn2_scale, bn2_bias, out);
}